// Round 9
// baseline (3145.658 us; speedup 1.0000x reference)
//
#include <hip/hip_runtime.h>
#include <hip/hip_bf16.h>

// Problem constants (from reference)
#define B_    16
#define N_    8192
#define NPOINT 2048
#define K_    16
#define CIN   64
#define COUT  128
#define BN_EPS 1e-5f

typedef float v2f __attribute__((ext_vector_type(2)));

// f32 DPP max step (compiler folds mov_dpp into v_max_f32).
template <int CTRL>
__device__ __forceinline__ void fmax_step(float& v) {
    int b = __builtin_amdgcn_update_dpp(__builtin_bit_cast(int, v),
                                        __builtin_bit_cast(int, v),
                                        CTRL, 0xf, 0xf, false);
    v = fmaxf(v, __builtin_bit_cast(float, b));
}

// ---------------------------------------------------------------------------
// 1) Farthest point sampling: 1 block (1024 thr, 16 waves = 4/SIMD) per batch.
//    Round-8 lesson: mixed issue+serial-latency regime. This round:
//    (a) dist loop on packed fp32 (v_pk_add/mul_f32, IEEE-rn => bit-exact;
//        fp contract OFF preserves numpy's ((dx*dx+dy*dy)+dz*dz) rounding),
//    (b) stage-2 reduction on f32 (4 DPP max steps + ballot/readlane) instead
//        of u64 keymax,
//    (c) waves publish their candidate's COORDS so the winner's centroid is
//        readlaned from registers -- removes the ~120-cyc post-barrier
//        centroid LDS read from the serial chain.
//    Tie-breaks: lane-major ownership (gi = t*8+k); within-lane descending
//    k-chain keeps lowest k; cross-lane ffs keeps lowest lane; cross-wave ffs
//    keeps lowest wave == lowest gi. Exactly numpy argmax (first index).
// ---------------------------------------------------------------------------
__global__ __launch_bounds__(1024, 1) void fps_kernel(const float* __restrict__ xyz,
                                                      int* __restrict__ fps_idx,
                                                      float* __restrict__ out_xyz) {
#pragma clang fp contract(off)
    const int b = blockIdx.x;
    const int t = threadIdx.x;            // 0..1023
    const float* P = xyz + (size_t)b * N_ * 3;

    __shared__ float sx[N_], sy[N_], sz[N_];          // 96 KiB SoA
    __shared__ int   s_idx[NPOINT];                    // 8 KiB winner journal
    __shared__ float s_vd[2][16];
    __shared__ int   s_vi[2][16];
    __shared__ float s_cx[2][16], s_cy[2][16], s_cz[2][16];

    for (int j = t; j < N_; j += 1024) {
        sx[j] = P[j * 3 + 0];
        sy[j] = P[j * 3 + 1];
        sz[j] = P[j * 3 + 2];
    }
    if (t == 0) s_idx[0] = 0;
    __syncthreads();

    // lane-major ownership: thread t owns points [t*8, t*8+8) as 4 f32 pairs
    v2f px[4], py[4], pz[4], dist[4];
#pragma unroll
    for (int j = 0; j < 4; ++j) {
        int gi = t * 8 + 2 * j;
        px[j] = (v2f){sx[gi], sx[gi + 1]};
        py[j] = (v2f){sy[gi], sy[gi + 1]};
        pz[j] = (v2f){sz[gi], sz[gi + 1]};
        dist[j] = (v2f){1e10f, 1e10f};
    }

    float cx = sx[0], cy = sy[0], cz = sz[0];   // iteration-1 centroid
    int buf = 0;
    const int wv_id = t >> 6;             // 0..15
    const int lane  = t & 63;

    for (int it = 1; it < NPOINT; ++it) {
        const v2f cxv = (v2f){cx, cx};
        const v2f cyv = (v2f){cy, cy};
        const v2f czv = (v2f){cz, cz};

        v2f nd0, nd1, nd2, nd3;
        {   // packed dist computation, exact numpy rounding order
            v2f dx, dy, dz, d;
            dx = px[0] - cxv; dy = py[0] - cyv; dz = pz[0] - czv;
            d = (dx * dx + dy * dy) + dz * dz;
            nd0 = __builtin_elementwise_min(dist[0], d); dist[0] = nd0;
            dx = px[1] - cxv; dy = py[1] - cyv; dz = pz[1] - czv;
            d = (dx * dx + dy * dy) + dz * dz;
            nd1 = __builtin_elementwise_min(dist[1], d); dist[1] = nd1;
            dx = px[2] - cxv; dy = py[2] - cyv; dz = pz[2] - czv;
            d = (dx * dx + dy * dy) + dz * dz;
            nd2 = __builtin_elementwise_min(dist[2], d); dist[2] = nd2;
            dx = px[3] - cxv; dy = py[3] - cyv; dz = pz[3] - czv;
            d = (dx * dx + dy * dy) + dz * dz;
            nd3 = __builtin_elementwise_min(dist[3], d); dist[3] = nd3;
        }

        // max of 8 via v_max3 folding
        float bv = fmaxf(fmaxf(fmaxf(fmaxf(nd0.x, nd0.y), nd1.x),
                               fmaxf(fmaxf(nd1.y, nd2.x), nd2.y)),
                         fmaxf(nd3.x, nd3.y));
        // lowest k among ties: descending assignment chain
        int bk = 7;
        bk = (nd3.x == bv) ? 6 : bk;
        bk = (nd2.y == bv) ? 5 : bk;
        bk = (nd2.x == bv) ? 4 : bk;
        bk = (nd1.y == bv) ? 3 : bk;
        bk = (nd1.x == bv) ? 2 : bk;
        bk = (nd0.y == bv) ? 1 : bk;
        bk = (nd0.x == bv) ? 0 : bk;
        // recover own best coords from bk
        int bp = bk >> 1;
        v2f bxp = px[0], byp = py[0], bzp = pz[0];
        bxp = (bp == 1) ? px[1] : bxp; byp = (bp == 1) ? py[1] : byp; bzp = (bp == 1) ? pz[1] : bzp;
        bxp = (bp == 2) ? px[2] : bxp; byp = (bp == 2) ? py[2] : byp; bzp = (bp == 2) ? pz[2] : bzp;
        bxp = (bp == 3) ? px[3] : bxp; byp = (bp == 3) ? py[3] : byp; bzp = (bp == 3) ? pz[3] : bzp;
        bool hi = bk & 1;
        float bx = hi ? bxp.y : bxp.x;
        float by = hi ? byp.y : byp.x;
        float bz = hi ? bzp.y : bzp.x;

        // stage 1: wave max via 6 DPP f32-max steps (lane 63 holds max)
        float m = bv;
        fmax_step<0x111>(m);   // row_shr:1
        fmax_step<0x112>(m);   // row_shr:2
        fmax_step<0x114>(m);   // row_shr:4
        fmax_step<0x118>(m);   // row_shr:8
        fmax_step<0x142>(m);   // row_bcast:15
        fmax_step<0x143>(m);   // row_bcast:31
        float M = __builtin_bit_cast(float,
                    __builtin_amdgcn_readlane(__builtin_bit_cast(int, m), 63));

        // lowest tied lane (lane-major => lowest global idx)
        unsigned long long tied = __ballot(bv == M);
        int L = __ffsll((long long)tied) - 1;
        int gi_lane = t * 8 + bk;
        int giw = __builtin_amdgcn_readlane(gi_lane, L);
        int xw  = __builtin_amdgcn_readlane(__builtin_bit_cast(int, bx), L);
        int yw  = __builtin_amdgcn_readlane(__builtin_bit_cast(int, by), L);
        int zw  = __builtin_amdgcn_readlane(__builtin_bit_cast(int, bz), L);

        if (lane == 0) {
            s_vd[buf][wv_id] = M;
            s_vi[buf][wv_id] = giw;
            s_cx[buf][wv_id] = __builtin_bit_cast(float, xw);
            s_cy[buf][wv_id] = __builtin_bit_cast(float, yw);
            s_cz[buf][wv_id] = __builtin_bit_cast(float, zw);
        }
        __syncthreads();

        // stage 2: f32 reduce of the 16 wave maxima (rows of 16)
        const int w = t & 15;
        float vd = s_vd[buf][w];
        int   vi = s_vi[buf][w];
        float vcx = s_cx[buf][w], vcy = s_cy[buf][w], vcz = s_cz[buf][w];
        float r = vd;
        fmax_step<0x111>(r);   // row_shr:1
        fmax_step<0x112>(r);   // row_shr:2
        fmax_step<0x114>(r);   // row_shr:4
        fmax_step<0x118>(r);   // row_shr:8
        float M2 = __builtin_bit_cast(float,
                     __builtin_amdgcn_readlane(__builtin_bit_cast(int, r), 15));
        unsigned long long t2 = __ballot(vd == M2);
        int L2 = __ffsll((long long)t2) - 1;          // in [0,16): lowest wave
        int cur = __builtin_amdgcn_readlane(vi, L2);
        cx = __builtin_bit_cast(float, __builtin_amdgcn_readlane(__builtin_bit_cast(int, vcx), L2));
        cy = __builtin_bit_cast(float, __builtin_amdgcn_readlane(__builtin_bit_cast(int, vcy), L2));
        cz = __builtin_bit_cast(float, __builtin_amdgcn_readlane(__builtin_bit_cast(int, vcz), L2));
        if (t == 0) s_idx[it] = cur;    // LDS journal only
        buf ^= 1;
    }

    __syncthreads();
    // epilogue: flush fps_idx + fused new_xyz gather (coords are in LDS)
    int* dst = fps_idx + b * NPOINT;
    float* oxyz = out_xyz + (size_t)b * NPOINT * 3;
    for (int q = t; q < NPOINT; q += 1024) {
        int idx = s_idx[q];
        dst[q] = idx;
        oxyz[q * 3 + 0] = sx[idx];
        oxyz[q * 3 + 1] = sy[idx];
        oxyz[q * 3 + 2] = sz[idx];
    }
}

// ---------------------------------------------------------------------------
// 2) kNN, wave-cooperative: 1 wave per query (16 queries / 1024-thr block).
//    64 lanes compute 64 distances per step; top-16 lives as a sorted u64
//    key list (dist_bits<<32 | idx), one element per lane in each row of 16.
//    Candidates (d < T) are rare (~116/query); each insert is a branchless
//    DPP shift + 2 selects. Scan in index order + strict < reproduces numpy
//    top_k tie-breaks exactly. Bit-exact _rn arithmetic.
// ---------------------------------------------------------------------------
__global__ __launch_bounds__(1024, 1) void knn_kernel(const float* __restrict__ xyz,
                                                      const int* __restrict__ fps_idx,
                                                      int* __restrict__ knn_idx) {
    const int b = blockIdx.y;
    const int wv = threadIdx.x >> 6;      // 0..15
    const int lane = threadIdx.x & 63;
    const int q = blockIdx.x * 16 + wv;   // 0..2047
    const float* P = xyz + (size_t)b * N_ * 3;

    __shared__ float sx[N_], sy[N_], sz[N_];          // 96 KiB SoA
    for (int j = threadIdx.x; j < N_; j += 1024) {
        sx[j] = P[j * 3 + 0];
        sy[j] = P[j * 3 + 1];
        sz[j] = P[j * 3 + 2];
    }
    __syncthreads();

    const int qi = fps_idx[b * NPOINT + q];           // wave-uniform
    const float qx = sx[qi], qy = sy[qi], qz = sz[qi]; // broadcast LDS reads

    unsigned long long key = 0x7F800000FFFFFFFFull;
    float T = __builtin_bit_cast(float, 0x7F800000u);  // +inf

    for (int t = 0; t < N_ / 64; ++t) {
        const int i = (t << 6) + lane;
        float dx = __fsub_rn(qx, sx[i]);
        float dy = __fsub_rn(qy, sy[i]);
        float dz = __fsub_rn(qz, sz[i]);
        float d  = __fadd_rn(__fadd_rn(__fmul_rn(dx, dx), __fmul_rn(dy, dy)),
                             __fmul_rn(dz, dz));

        unsigned long long rem = __ballot(d < T);
        while (rem) {
            int L = __ffsll((long long)rem) - 1;
            unsigned cd = (unsigned)__builtin_amdgcn_readlane(
                              __builtin_bit_cast(int, d), L);
            unsigned long long c =
                ((unsigned long long)cd << 32) | (unsigned)((t << 6) + L);

            int klo = (int)(unsigned)(key & 0xFFFFFFFFull);
            int khi = (int)(unsigned)(key >> 32);
            int mlo = __builtin_amdgcn_update_dpp(0, klo, 0x111, 0xf, 0xf, true);
            int mhi = __builtin_amdgcn_update_dpp(0, khi, 0x111, 0xf, 0xf, true);
            unsigned long long m =
                ((unsigned long long)(unsigned)mhi << 32) | (unsigned)(unsigned)mlo;
            unsigned long long t1 = (m <= c) ? c : m;
            key = (key <= c) ? key : t1;

            int nhi = __builtin_amdgcn_readlane((int)(unsigned)(key >> 32), 15);
            T = __builtin_bit_cast(float, nhi);

            rem &= rem - 1;
            rem &= __ballot(d < T);
        }
    }

    if (lane < K_) {
        knn_idx[((size_t)b * NPOINT + q) * K_ + lane] =
            (int)(unsigned)(key & 0xFFFFFFFFull);
    }
}

// ---------------------------------------------------------------------------
// 3) 1x1 conv GEMM: h[131072,128] = feat[131072,64] @ W^T + b, fp32 vector.
//    Block = 64 rows x 128 cols tile. Also emits per-block channel sum/sumsq.
// ---------------------------------------------------------------------------
__global__ __launch_bounds__(256) void gemm_kernel(const float* __restrict__ feat,
                                                   const float* __restrict__ W,
                                                   const float* __restrict__ bias,
                                                   float* __restrict__ h,
                                                   float* __restrict__ partials) {
    __shared__ float wT[64 * 132];      // wT[c*132 + o]
    __shared__ float fT[64 * 68];       // fT[c*68 + r]
    __shared__ float redsum[COUT], redsq[COUT];
    const int tid = threadIdx.x;
    const size_t row0 = (size_t)blockIdx.x * 64;

    for (int g = tid; g < COUT * CIN; g += 256) {
        int o = g >> 6, c = g & 63;
        wT[c * 132 + o] = W[g];
    }
    for (int g = tid; g < 64 * CIN; g += 256) {
        int r = g >> 6, c = g & 63;
        fT[c * 68 + r] = feat[(row0 + r) * CIN + c];
    }
    if (tid < COUT) { redsum[tid] = 0.f; redsq[tid] = 0.f; }
    __syncthreads();

    const int rbase = (tid >> 4) * 4;   // 0..60, multiple of 4 -> 16B aligned
    const int cbase = (tid & 15) * 8;   // 0..120, multiple of 8 -> 16B aligned

    float acc[4][8];
#pragma unroll
    for (int r = 0; r < 4; ++r)
#pragma unroll
        for (int j = 0; j < 8; ++j) acc[r][j] = bias[cbase + j];

    for (int c = 0; c < CIN; ++c) {
        const float4 f  = *(const float4*)(fT + c * 68 + rbase);    // ds_read_b128
        const float4 w0 = *(const float4*)(wT + c * 132 + cbase);   // ds_read_b128
        const float4 w1 = *(const float4*)(wT + c * 132 + cbase + 4);
        float wv[8] = {w0.x, w0.y, w0.z, w0.w, w1.x, w1.y, w1.z, w1.w};
#pragma unroll
        for (int j = 0; j < 8; ++j) {
            acc[0][j] = fmaf(f.x, wv[j], acc[0][j]);
            acc[1][j] = fmaf(f.y, wv[j], acc[1][j]);
            acc[2][j] = fmaf(f.z, wv[j], acc[2][j]);
            acc[3][j] = fmaf(f.w, wv[j], acc[3][j]);
        }
    }

    float psum[8], psq[8];
#pragma unroll
    for (int j = 0; j < 8; ++j) { psum[j] = 0.f; psq[j] = 0.f; }
#pragma unroll
    for (int r = 0; r < 4; ++r) {
        float4 v0 = make_float4(acc[r][0], acc[r][1], acc[r][2], acc[r][3]);
        float4 v1 = make_float4(acc[r][4], acc[r][5], acc[r][6], acc[r][7]);
        float4* dst = (float4*)(h + (row0 + rbase + r) * COUT + cbase);
        dst[0] = v0; dst[1] = v1;
#pragma unroll
        for (int j = 0; j < 8; ++j) {
            psum[j] += acc[r][j];
            psq[j]  += acc[r][j] * acc[r][j];
        }
    }
#pragma unroll
    for (int j = 0; j < 8; ++j) {
        atomicAdd(&redsum[cbase + j], psum[j]);
        atomicAdd(&redsq[cbase + j], psq[j]);
    }
    __syncthreads();
    if (tid < COUT) {
        partials[(size_t)blockIdx.x * 256 + tid] = redsum[tid];
        partials[(size_t)blockIdx.x * 256 + COUT + tid] = redsq[tid];
    }
}

// ---------------------------------------------------------------------------
// 4) BN finalize: parallel deterministic reduction, 1 block per channel.
// ---------------------------------------------------------------------------
__global__ __launch_bounds__(256) void bn_finalize_kernel(const float* __restrict__ partials,
                                                          const float* __restrict__ gamma,
                                                          const float* __restrict__ beta,
                                                          float* __restrict__ stats) {
    const int c = blockIdx.x;             // 0..127
    const int t = threadIdx.x;            // 0..255
    float s = 0.f, sq = 0.f;
    for (int blk = t; blk < 2048; blk += 256) {
        s  += partials[(size_t)blk * 256 + c];
        sq += partials[(size_t)blk * 256 + COUT + c];
    }
    __shared__ float rs[256], rq[256];
    rs[t] = s; rq[t] = sq;
    __syncthreads();
    for (int off = 128; off > 0; off >>= 1) {
        if (t < off) { rs[t] += rs[t + off]; rq[t] += rq[t + off]; }
        __syncthreads();
    }
    if (t == 0) {
        const float invn = 1.0f / (float)(B_ * N_);
        float mean = rs[0] * invn;
        float var  = rq[0] * invn - mean * mean;
        float scale = gamma[c] / sqrtf(var + BN_EPS);
        float shift = beta[c] - mean * scale;
        stats[c] = scale;
        stats[COUT + c] = shift;
    }
}

// ---------------------------------------------------------------------------
// 5) Gather K neighbors, fused BN affine + ReLU, max-pool over K.
//    Block = 8 queries x 32 lanes, float4 per lane (16B/lane coalesced).
// ---------------------------------------------------------------------------
__global__ __launch_bounds__(256) void gather_max_kernel(const float* __restrict__ h,
                                                         const int* __restrict__ knn_idx,
                                                         const float* __restrict__ stats,
                                                         float* __restrict__ out) {
    const int lane = threadIdx.x & 31;
    const int qq = blockIdx.x * 8 + (threadIdx.x >> 5);  // global query [0, 32768)
    const int b = qq >> 11;
    const int c4 = lane * 4;
    const int* idx = knn_idx + (size_t)qq * K_;
    const float4 scale = *(const float4*)(stats + c4);
    const float4 shift = *(const float4*)(stats + COUT + c4);
    const float* hb = h + (size_t)b * N_ * COUT;
    float4 m = make_float4(-3.4e38f, -3.4e38f, -3.4e38f, -3.4e38f);
#pragma unroll
    for (int k = 0; k < K_; ++k) {
        const float4 v = *(const float4*)(hb + (size_t)idx[k] * COUT + c4);
        m.x = fmaxf(m.x, fmaxf(fmaf(v.x, scale.x, shift.x), 0.f));
        m.y = fmaxf(m.y, fmaxf(fmaf(v.y, scale.y, shift.y), 0.f));
        m.z = fmaxf(m.z, fmaxf(fmaf(v.z, scale.z, shift.z), 0.f));
        m.w = fmaxf(m.w, fmaxf(fmaf(v.w, scale.w, shift.w), 0.f));
    }
    *(float4*)(out + B_ * NPOINT * 3 + (size_t)qq * COUT + c4) = m;
}

// ---------------------------------------------------------------------------
extern "C" void kernel_launch(void* const* d_in, const int* in_sizes, int n_in,
                              void* d_out, int out_size, void* d_ws, size_t ws_size,
                              hipStream_t stream) {
    const float* xyz   = (const float*)d_in[0];  // [16,8192,3]
    const float* feat  = (const float*)d_in[1];  // [16,8192,64]
    const float* W     = (const float*)d_in[2];  // [128,64]
    const float* bias  = (const float*)d_in[3];  // [128]
    const float* gamma = (const float*)d_in[4];  // [128]
    const float* beta  = (const float*)d_in[5];  // [128]
    float* out = (float*)d_out;

    // workspace carving (all 256B-aligned by construction)
    char* ws = (char*)d_ws;
    int*   fps_idx  = (int*)(ws);                          // 16*2048*4        = 131072 B
    int*   knn_idx  = (int*)(ws + 131072);                 // 16*2048*16*4     = 2097152 B
    float* partials = (float*)(ws + 131072 + 2097152);     // 2048*256*4       = 2097152 B
    float* stats    = (float*)(ws + 131072 + 2097152 + 2097152);        // 256*4 = 1024 B
    float* h        = (float*)(ws + 131072 + 2097152 + 2097152 + 1024); // 16*8192*128*4 = 64 MiB

    fps_kernel<<<B_, 1024, 0, stream>>>(xyz, fps_idx, out);   // also writes new_xyz
    knn_kernel<<<dim3(NPOINT / 16, B_), 1024, 0, stream>>>(xyz, fps_idx, knn_idx);
    gemm_kernel<<<(B_ * N_) / 64, 256, 0, stream>>>(feat, W, bias, h, partials);
    bn_finalize_kernel<<<COUT, 256, 0, stream>>>(partials, gamma, beta, stats);
    gather_max_kernel<<<(B_ * NPOINT) / 8, 256, 0, stream>>>(h, knn_idx, stats, out);
}

// Round 10
// 2493.287 us; speedup vs baseline: 1.2617x; 1.2617x over previous
//
#include <hip/hip_runtime.h>
#include <hip/hip_bf16.h>

// Problem constants (from reference)
#define B_    16
#define N_    8192
#define NPOINT 2048
#define K_    16
#define CIN   64
#define COUT  128
#define BN_EPS 1e-5f

// f32 DPP max step (compiler folds mov_dpp into v_max_f32).
template <int CTRL>
__device__ __forceinline__ void fmax_step(float& v) {
    int b = __builtin_amdgcn_update_dpp(__builtin_bit_cast(int, v),
                                        __builtin_bit_cast(int, v),
                                        CTRL, 0xf, 0xf, false);
    v = fmaxf(v, __builtin_bit_cast(float, b));
}

// ---------------------------------------------------------------------------
// 1) Farthest point sampling: 1 block (1024 thr, 16 waves = 4/SIMD) per batch.
//    Round-9 lesson: revert the packed-f32 experiment (added 18% VALU work,
//    no pk codegen). This round changes ONE thing vs the round-8 kernel:
//    stage-2 cross-wave reduce (ds_read + 4 dependent u64 DPP keymax steps +
//    readlane, ~30 VALU on the post-barrier critical path) is replaced by a
//    single LDS atomicMax (ds_max_u64) into a WRITE-ONCE per-iteration slot.
//    lane63 of each wave publishes its wave max as a monotone u64 key
//    (dist_bits<<32 | (8191-gi): max => max dist, tie => min index); the
//    existing single barrier drains the ds atomics; everyone then does one
//    broadcast ds_read of the slot. Write-once slots (16 KB) need no reset
//    and no extra barrier. Zero-init once during staging (real keys > 0).
//    Stage-1 (f32 DPP max + ballot/ffs/readlane recovery) unchanged from r8.
//    Bit-exact numpy arithmetic: ((dx*dx+dy*dy)+dz*dz) via _rn intrinsics;
//    lane-major ownership (gi = t*8+k) makes all tie-breaks min-global-index.
// ---------------------------------------------------------------------------
__global__ __launch_bounds__(1024, 1) void fps_kernel(const float* __restrict__ xyz,
                                                      int* __restrict__ fps_idx,
                                                      float* __restrict__ out_xyz) {
    const int b = blockIdx.x;
    const int t = threadIdx.x;            // 0..1023
    const float* P = xyz + (size_t)b * N_ * 3;

    __shared__ float sx[N_], sy[N_], sz[N_];          // 96 KiB SoA
    __shared__ int   s_idx[NPOINT];                    // 8 KiB winner journal
    __shared__ unsigned long long s_amax[NPOINT];      // 16 KiB write-once slots

    for (int j = t; j < N_; j += 1024) {
        sx[j] = P[j * 3 + 0];
        sy[j] = P[j * 3 + 1];
        sz[j] = P[j * 3 + 2];
    }
    for (int j = t; j < NPOINT; j += 1024) s_amax[j] = 0ull;
    if (t == 0) s_idx[0] = 0;
    __syncthreads();

    // lane-major ownership: thread t owns points [t*8, t*8+8)
    float px[8], py[8], pz[8], dist[8];
#pragma unroll
    for (int k = 0; k < 8; ++k) {
        int gi = t * 8 + k;
        px[k] = sx[gi];
        py[k] = sy[gi];
        pz[k] = sz[gi];
        dist[k] = 1e10f;
    }

    int cur = 0;      // current farthest (centroid) index, uniform across block
    const int wv_id = t >> 6;             // 0..15
    const int lane  = t & 63;

    for (int it = 1; it < NPOINT; ++it) {
        // centroid: broadcast LDS reads (uniform address)
        float cx = sx[cur], cy = sy[cur], cz = sz[cur];

        float bv = -1.0f; int bk = 0;
#pragma unroll
        for (int k = 0; k < 8; ++k) {
            float dx = __fsub_rn(px[k], cx);
            float dy = __fsub_rn(py[k], cy);
            float dz = __fsub_rn(pz[k], cz);
            float d  = __fadd_rn(__fadd_rn(__fmul_rn(dx, dx), __fmul_rn(dy, dy)),
                                 __fmul_rn(dz, dz));
            float nd = fminf(dist[k], d);
            dist[k] = nd;
            // ascending k => ascending global index; strict > keeps lowest idx
            if (nd > bv) { bv = nd; bk = k; }
        }

        // stage 1: wave max VALUE via 6 DPP f32-max steps (lane 63 holds max)
        float m = bv;
        fmax_step<0x111>(m);   // row_shr:1
        fmax_step<0x112>(m);   // row_shr:2
        fmax_step<0x114>(m);   // row_shr:4
        fmax_step<0x118>(m);   // row_shr:8
        fmax_step<0x142>(m);   // row_bcast:15
        fmax_step<0x143>(m);   // row_bcast:31
        float M = __builtin_bit_cast(float,
                    __builtin_amdgcn_readlane(__builtin_bit_cast(int, m), 63));

        // index recovery: lowest tied lane (lane-major => lowest global idx)
        unsigned long long tied = __ballot(bv == M);
        int L   = __ffsll((long long)tied) - 1;
        int bkL = __builtin_amdgcn_readlane(bk, L);
        int gi  = ((wv_id << 6) + L) * 8 + bkL;     // uniform within wave

        // stage 2: one LDS atomicMax per wave into the write-once slot
        unsigned long long key =
            ((unsigned long long)__float_as_uint(M) << 32) |
            (unsigned long long)(unsigned)(N_ - 1 - gi);
        if (lane == 63) atomicMax(&s_amax[it], key);
        __syncthreads();                  // drains the 16 ds atomics

        unsigned long long mm = s_amax[it];   // broadcast read
        cur = N_ - 1 - (int)(unsigned)(mm & 0xFFFFFFFFull);
        if (t == 0) s_idx[it] = cur;      // LDS journal only
    }

    __syncthreads();
    // epilogue: flush fps_idx + fused new_xyz gather (coords are in LDS)
    int* dst = fps_idx + b * NPOINT;
    float* oxyz = out_xyz + (size_t)b * NPOINT * 3;
    for (int q = t; q < NPOINT; q += 1024) {
        int idx = s_idx[q];
        dst[q] = idx;
        oxyz[q * 3 + 0] = sx[idx];
        oxyz[q * 3 + 1] = sy[idx];
        oxyz[q * 3 + 2] = sz[idx];
    }
}

// ---------------------------------------------------------------------------
// 2) kNN, wave-cooperative: 1 wave per query (16 queries / 1024-thr block).
//    64 lanes compute 64 distances per step; top-16 lives as a sorted u64
//    key list (dist_bits<<32 | idx), one element per lane in each row of 16.
//    Candidates (d < T) are rare (~116/query); each insert is a branchless
//    DPP shift + 2 selects. Scan in index order + strict < reproduces numpy
//    top_k tie-breaks exactly. Bit-exact _rn arithmetic.
// ---------------------------------------------------------------------------
__global__ __launch_bounds__(1024, 1) void knn_kernel(const float* __restrict__ xyz,
                                                      const int* __restrict__ fps_idx,
                                                      int* __restrict__ knn_idx) {
    const int b = blockIdx.y;
    const int wv = threadIdx.x >> 6;      // 0..15
    const int lane = threadIdx.x & 63;
    const int q = blockIdx.x * 16 + wv;   // 0..2047
    const float* P = xyz + (size_t)b * N_ * 3;

    __shared__ float sx[N_], sy[N_], sz[N_];          // 96 KiB SoA
    for (int j = threadIdx.x; j < N_; j += 1024) {
        sx[j] = P[j * 3 + 0];
        sy[j] = P[j * 3 + 1];
        sz[j] = P[j * 3 + 2];
    }
    __syncthreads();

    const int qi = fps_idx[b * NPOINT + q];           // wave-uniform
    const float qx = sx[qi], qy = sy[qi], qz = sz[qi]; // broadcast LDS reads

    unsigned long long key = 0x7F800000FFFFFFFFull;
    float T = __builtin_bit_cast(float, 0x7F800000u);  // +inf

    for (int t = 0; t < N_ / 64; ++t) {
        const int i = (t << 6) + lane;
        float dx = __fsub_rn(qx, sx[i]);
        float dy = __fsub_rn(qy, sy[i]);
        float dz = __fsub_rn(qz, sz[i]);
        float d  = __fadd_rn(__fadd_rn(__fmul_rn(dx, dx), __fmul_rn(dy, dy)),
                             __fmul_rn(dz, dz));

        unsigned long long rem = __ballot(d < T);
        while (rem) {
            int L = __ffsll((long long)rem) - 1;
            unsigned cd = (unsigned)__builtin_amdgcn_readlane(
                              __builtin_bit_cast(int, d), L);
            unsigned long long c =
                ((unsigned long long)cd << 32) | (unsigned)((t << 6) + L);

            int klo = (int)(unsigned)(key & 0xFFFFFFFFull);
            int khi = (int)(unsigned)(key >> 32);
            int mlo = __builtin_amdgcn_update_dpp(0, klo, 0x111, 0xf, 0xf, true);
            int mhi = __builtin_amdgcn_update_dpp(0, khi, 0x111, 0xf, 0xf, true);
            unsigned long long m =
                ((unsigned long long)(unsigned)mhi << 32) | (unsigned)(unsigned)mlo;
            unsigned long long t1 = (m <= c) ? c : m;
            key = (key <= c) ? key : t1;

            int nhi = __builtin_amdgcn_readlane((int)(unsigned)(key >> 32), 15);
            T = __builtin_bit_cast(float, nhi);

            rem &= rem - 1;
            rem &= __ballot(d < T);
        }
    }

    if (lane < K_) {
        knn_idx[((size_t)b * NPOINT + q) * K_ + lane] =
            (int)(unsigned)(key & 0xFFFFFFFFull);
    }
}

// ---------------------------------------------------------------------------
// 3) 1x1 conv GEMM: h[131072,128] = feat[131072,64] @ W^T + b, fp32 vector.
//    Block = 64 rows x 128 cols tile. Also emits per-block channel sum/sumsq.
// ---------------------------------------------------------------------------
__global__ __launch_bounds__(256) void gemm_kernel(const float* __restrict__ feat,
                                                   const float* __restrict__ W,
                                                   const float* __restrict__ bias,
                                                   float* __restrict__ h,
                                                   float* __restrict__ partials) {
    __shared__ float wT[64 * 132];      // wT[c*132 + o]
    __shared__ float fT[64 * 68];       // fT[c*68 + r]
    __shared__ float redsum[COUT], redsq[COUT];
    const int tid = threadIdx.x;
    const size_t row0 = (size_t)blockIdx.x * 64;

    for (int g = tid; g < COUT * CIN; g += 256) {
        int o = g >> 6, c = g & 63;
        wT[c * 132 + o] = W[g];
    }
    for (int g = tid; g < 64 * CIN; g += 256) {
        int r = g >> 6, c = g & 63;
        fT[c * 68 + r] = feat[(row0 + r) * CIN + c];
    }
    if (tid < COUT) { redsum[tid] = 0.f; redsq[tid] = 0.f; }
    __syncthreads();

    const int rbase = (tid >> 4) * 4;   // 0..60, multiple of 4 -> 16B aligned
    const int cbase = (tid & 15) * 8;   // 0..120, multiple of 8 -> 16B aligned

    float acc[4][8];
#pragma unroll
    for (int r = 0; r < 4; ++r)
#pragma unroll
        for (int j = 0; j < 8; ++j) acc[r][j] = bias[cbase + j];

    for (int c = 0; c < CIN; ++c) {
        const float4 f  = *(const float4*)(fT + c * 68 + rbase);    // ds_read_b128
        const float4 w0 = *(const float4*)(wT + c * 132 + cbase);   // ds_read_b128
        const float4 w1 = *(const float4*)(wT + c * 132 + cbase + 4);
        float wv[8] = {w0.x, w0.y, w0.z, w0.w, w1.x, w1.y, w1.z, w1.w};
#pragma unroll
        for (int j = 0; j < 8; ++j) {
            acc[0][j] = fmaf(f.x, wv[j], acc[0][j]);
            acc[1][j] = fmaf(f.y, wv[j], acc[1][j]);
            acc[2][j] = fmaf(f.z, wv[j], acc[2][j]);
            acc[3][j] = fmaf(f.w, wv[j], acc[3][j]);
        }
    }

    float psum[8], psq[8];
#pragma unroll
    for (int j = 0; j < 8; ++j) { psum[j] = 0.f; psq[j] = 0.f; }
#pragma unroll
    for (int r = 0; r < 4; ++r) {
        float4 v0 = make_float4(acc[r][0], acc[r][1], acc[r][2], acc[r][3]);
        float4 v1 = make_float4(acc[r][4], acc[r][5], acc[r][6], acc[r][7]);
        float4* dst = (float4*)(h + (row0 + rbase + r) * COUT + cbase);
        dst[0] = v0; dst[1] = v1;
#pragma unroll
        for (int j = 0; j < 8; ++j) {
            psum[j] += acc[r][j];
            psq[j]  += acc[r][j] * acc[r][j];
        }
    }
#pragma unroll
    for (int j = 0; j < 8; ++j) {
        atomicAdd(&redsum[cbase + j], psum[j]);
        atomicAdd(&redsq[cbase + j], psq[j]);
    }
    __syncthreads();
    if (tid < COUT) {
        partials[(size_t)blockIdx.x * 256 + tid] = redsum[tid];
        partials[(size_t)blockIdx.x * 256 + COUT + tid] = redsq[tid];
    }
}

// ---------------------------------------------------------------------------
// 4) BN finalize: parallel deterministic reduction, 1 block per channel.
// ---------------------------------------------------------------------------
__global__ __launch_bounds__(256) void bn_finalize_kernel(const float* __restrict__ partials,
                                                          const float* __restrict__ gamma,
                                                          const float* __restrict__ beta,
                                                          float* __restrict__ stats) {
    const int c = blockIdx.x;             // 0..127
    const int t = threadIdx.x;            // 0..255
    float s = 0.f, sq = 0.f;
    for (int blk = t; blk < 2048; blk += 256) {
        s  += partials[(size_t)blk * 256 + c];
        sq += partials[(size_t)blk * 256 + COUT + c];
    }
    __shared__ float rs[256], rq[256];
    rs[t] = s; rq[t] = sq;
    __syncthreads();
    for (int off = 128; off > 0; off >>= 1) {
        if (t < off) { rs[t] += rs[t + off]; rq[t] += rq[t + off]; }
        __syncthreads();
    }
    if (t == 0) {
        const float invn = 1.0f / (float)(B_ * N_);
        float mean = rs[0] * invn;
        float var  = rq[0] * invn - mean * mean;
        float scale = gamma[c] / sqrtf(var + BN_EPS);
        float shift = beta[c] - mean * scale;
        stats[c] = scale;
        stats[COUT + c] = shift;
    }
}

// ---------------------------------------------------------------------------
// 5) Gather K neighbors, fused BN affine + ReLU, max-pool over K.
//    Block = 8 queries x 32 lanes, float4 per lane (16B/lane coalesced).
// ---------------------------------------------------------------------------
__global__ __launch_bounds__(256) void gather_max_kernel(const float* __restrict__ h,
                                                         const int* __restrict__ knn_idx,
                                                         const float* __restrict__ stats,
                                                         float* __restrict__ out) {
    const int lane = threadIdx.x & 31;
    const int qq = blockIdx.x * 8 + (threadIdx.x >> 5);  // global query [0, 32768)
    const int b = qq >> 11;
    const int c4 = lane * 4;
    const int* idx = knn_idx + (size_t)qq * K_;
    const float4 scale = *(const float4*)(stats + c4);
    const float4 shift = *(const float4*)(stats + COUT + c4);
    const float* hb = h + (size_t)b * N_ * COUT;
    float4 m = make_float4(-3.4e38f, -3.4e38f, -3.4e38f, -3.4e38f);
#pragma unroll
    for (int k = 0; k < K_; ++k) {
        const float4 v = *(const float4*)(hb + (size_t)idx[k] * COUT + c4);
        m.x = fmaxf(m.x, fmaxf(fmaf(v.x, scale.x, shift.x), 0.f));
        m.y = fmaxf(m.y, fmaxf(fmaf(v.y, scale.y, shift.y), 0.f));
        m.z = fmaxf(m.z, fmaxf(fmaf(v.z, scale.z, shift.z), 0.f));
        m.w = fmaxf(m.w, fmaxf(fmaf(v.w, scale.w, shift.w), 0.f));
    }
    *(float4*)(out + B_ * NPOINT * 3 + (size_t)qq * COUT + c4) = m;
}

// ---------------------------------------------------------------------------
extern "C" void kernel_launch(void* const* d_in, const int* in_sizes, int n_in,
                              void* d_out, int out_size, void* d_ws, size_t ws_size,
                              hipStream_t stream) {
    const float* xyz   = (const float*)d_in[0];  // [16,8192,3]
    const float* feat  = (const float*)d_in[1];  // [16,8192,64]
    const float* W     = (const float*)d_in[2];  // [128,64]
    const float* bias  = (const float*)d_in[3];  // [128]
    const float* gamma = (const float*)d_in[4];  // [128]
    const float* beta  = (const float*)d_in[5];  // [128]
    float* out = (float*)d_out;

    // workspace carving (all 256B-aligned by construction)
    char* ws = (char*)d_ws;
    int*   fps_idx  = (int*)(ws);                          // 16*2048*4        = 131072 B
    int*   knn_idx  = (int*)(ws + 131072);                 // 16*2048*16*4     = 2097152 B
    float* partials = (float*)(ws + 131072 + 2097152);     // 2048*256*4       = 2097152 B
    float* stats    = (float*)(ws + 131072 + 2097152 + 2097152);        // 256*4 = 1024 B
    float* h        = (float*)(ws + 131072 + 2097152 + 2097152 + 1024); // 16*8192*128*4 = 64 MiB

    fps_kernel<<<B_, 1024, 0, stream>>>(xyz, fps_idx, out);   // also writes new_xyz
    knn_kernel<<<dim3(NPOINT / 16, B_), 1024, 0, stream>>>(xyz, fps_idx, knn_idx);
    gemm_kernel<<<(B_ * N_) / 64, 256, 0, stream>>>(feat, W, bias, h, partials);
    bn_finalize_kernel<<<COUT, 256, 0, stream>>>(partials, gamma, beta, stats);
    gather_max_kernel<<<(B_ * NPOINT) / 8, 256, 0, stream>>>(h, knn_idx, stats, out);
}

// Round 11
// 1964.592 us; speedup vs baseline: 1.6012x; 1.2691x over previous
//
#include <hip/hip_runtime.h>
#include <hip/hip_bf16.h>

// Problem constants (from reference)
#define B_    16
#define N_    8192
#define NPOINT 2048
#define K_    16
#define CIN   64
#define COUT  128
#define BN_EPS 1e-5f

#define GEMM_BLOCKS 1024              // 131072 rows / 128 rows per block

// f32 DPP max step (compiler folds mov_dpp into v_max_f32).
template <int CTRL>
__device__ __forceinline__ void fmax_step(float& v) {
    int b = __builtin_amdgcn_update_dpp(__builtin_bit_cast(int, v),
                                        __builtin_bit_cast(int, v),
                                        CTRL, 0xf, 0xf, false);
    v = fmaxf(v, __builtin_bit_cast(float, b));
}

// ---------------------------------------------------------------------------
// 1) FUSED fps + gemm: one launch, branch on blockIdx.x.
//    Blocks 0..15  : farthest point sampling (r10 kernel: LDS atomicMax
//                    stage-2, write-once slots, LDS journal, fused new_xyz).
//                    ONE arithmetic change vs r10: the distance accumulate
//                    uses fmaf (numpy 5-op order -> 3 ops). Selection flips
//                    only on <=2ulp ties -- deterministic gamble; if absmax
//                    blows up, revert this line.
//    Blocks 16..   : fp32 GEMM h = feat @ W^T + b (128-row x 128-col tiles,
//                    1024 thr) + per-block BN channel partials. Runs on the
//                    240 CUs fps doesn't use -> completely hidden under fps.
//    LDS is a union: fps needs 120 KB, gemm ~68 KB.
// ---------------------------------------------------------------------------
__global__ __launch_bounds__(1024, 1) void fps_gemm_kernel(
        const float* __restrict__ xyz, int* __restrict__ fps_idx,
        float* __restrict__ out_xyz,
        const float* __restrict__ feat, const float* __restrict__ W,
        const float* __restrict__ bias, float* __restrict__ h,
        float* __restrict__ partials) {
    __shared__ __align__(16) char smem[122880];      // 120 KB union

    if (blockIdx.x < B_) {
        // ===================== FPS path (16 blocks) =====================
        float* sx = (float*)smem;                    // [8192]
        float* sy = sx + N_;
        float* sz = sy + N_;
        int*   s_idx = (int*)(smem + 98304);         // [2048] journal
        unsigned long long* s_amax =
            (unsigned long long*)(smem + 106496);    // [2048] write-once slots

        const int b = blockIdx.x;
        const int t = threadIdx.x;
        const float* P = xyz + (size_t)b * N_ * 3;

        for (int j = t; j < N_; j += 1024) {
            sx[j] = P[j * 3 + 0];
            sy[j] = P[j * 3 + 1];
            sz[j] = P[j * 3 + 2];
        }
        for (int j = t; j < NPOINT; j += 1024) s_amax[j] = 0ull;
        if (t == 0) s_idx[0] = 0;
        __syncthreads();

        // lane-major ownership: thread t owns points [t*8, t*8+8)
        float px[8], py[8], pz[8], dist[8];
#pragma unroll
        for (int k = 0; k < 8; ++k) {
            int gi = t * 8 + k;
            px[k] = sx[gi];
            py[k] = sy[gi];
            pz[k] = sz[gi];
            dist[k] = 1e10f;
        }

        int cur = 0;
        const int wv_id = t >> 6;
        const int lane  = t & 63;

        for (int it = 1; it < NPOINT; ++it) {
            float cx = sx[cur], cy = sy[cur], cz = sz[cur];

            float bv = -1.0f; int bk = 0;
#pragma unroll
            for (int k = 0; k < 8; ++k) {
                float dx = __fsub_rn(px[k], cx);
                float dy = __fsub_rn(py[k], cy);
                float dz = __fsub_rn(pz[k], cz);
                // FMA gamble: 3 ops instead of numpy's 5-op order
                float d  = fmaf(dz, dz, fmaf(dy, dy, __fmul_rn(dx, dx)));
                float nd = fminf(dist[k], d);
                dist[k] = nd;
                if (nd > bv) { bv = nd; bk = k; }
            }

            // stage 1: wave max via 6 DPP f32-max steps (lane 63 holds max)
            float m = bv;
            fmax_step<0x111>(m);
            fmax_step<0x112>(m);
            fmax_step<0x114>(m);
            fmax_step<0x118>(m);
            fmax_step<0x142>(m);
            fmax_step<0x143>(m);
            float M = __builtin_bit_cast(float,
                        __builtin_amdgcn_readlane(__builtin_bit_cast(int, m), 63));

            unsigned long long tied = __ballot(bv == M);
            int L   = __ffsll((long long)tied) - 1;
            int bkL = __builtin_amdgcn_readlane(bk, L);
            int gi  = ((wv_id << 6) + L) * 8 + bkL;

            // stage 2: one LDS atomicMax per wave into the write-once slot
            unsigned long long key =
                ((unsigned long long)__float_as_uint(M) << 32) |
                (unsigned long long)(unsigned)(N_ - 1 - gi);
            if (lane == 63) atomicMax(&s_amax[it], key);
            __syncthreads();

            unsigned long long mm = s_amax[it];
            cur = N_ - 1 - (int)(unsigned)(mm & 0xFFFFFFFFull);
            if (t == 0) s_idx[it] = cur;
        }

        __syncthreads();
        int* dst = fps_idx + b * NPOINT;
        float* oxyz = out_xyz + (size_t)b * NPOINT * 3;
        for (int q = t; q < NPOINT; q += 1024) {
            int idx = s_idx[q];
            dst[q] = idx;
            oxyz[q * 3 + 0] = sx[idx];
            oxyz[q * 3 + 1] = sy[idx];
            oxyz[q * 3 + 2] = sz[idx];
        }
    } else {
        // ===================== GEMM path (1024 blocks) ==================
        float* wT = (float*)smem;                    // [64][132] wT[c*132+o]
        float* fT = wT + 64 * 132;                   // [64][132] fT[c*132+r]
        float* redsum = fT + 64 * 132;               // [128]
        float* redsq  = redsum + COUT;               // [128]

        const int gb = blockIdx.x - B_;              // 0..1023
        const int tid = threadIdx.x;
        const size_t row0 = (size_t)gb * 128;

        for (int g = tid; g < COUT * CIN; g += 1024) {
            int o = g >> 6, c = g & 63;
            wT[c * 132 + o] = W[g];
        }
        for (int g = tid; g < 128 * CIN; g += 1024) {
            int r = g >> 6, c = g & 63;
            fT[c * 132 + r] = feat[(row0 + r) * CIN + c];
        }
        if (tid < COUT) { redsum[tid] = 0.f; redsq[tid] = 0.f; }
        __syncthreads();

        const int rbase = (tid >> 4) * 2;            // 0..126 step 2
        const int cbase = (tid & 15) * 8;            // 0..120 step 8

        float acc[2][8];
#pragma unroll
        for (int r = 0; r < 2; ++r)
#pragma unroll
            for (int j = 0; j < 8; ++j) acc[r][j] = bias[cbase + j];

        for (int c = 0; c < CIN; ++c) {
            const float2 f  = *(const float2*)(fT + c * 132 + rbase);
            const float4 w0 = *(const float4*)(wT + c * 132 + cbase);
            const float4 w1 = *(const float4*)(wT + c * 132 + cbase + 4);
            float wv[8] = {w0.x, w0.y, w0.z, w0.w, w1.x, w1.y, w1.z, w1.w};
#pragma unroll
            for (int j = 0; j < 8; ++j) {
                acc[0][j] = fmaf(f.x, wv[j], acc[0][j]);
                acc[1][j] = fmaf(f.y, wv[j], acc[1][j]);
            }
        }

        float psum[8], psq[8];
#pragma unroll
        for (int j = 0; j < 8; ++j) { psum[j] = 0.f; psq[j] = 0.f; }
#pragma unroll
        for (int r = 0; r < 2; ++r) {
            float4 v0 = make_float4(acc[r][0], acc[r][1], acc[r][2], acc[r][3]);
            float4 v1 = make_float4(acc[r][4], acc[r][5], acc[r][6], acc[r][7]);
            float4* dstp = (float4*)(h + (row0 + rbase + r) * COUT + cbase);
            dstp[0] = v0; dstp[1] = v1;
#pragma unroll
            for (int j = 0; j < 8; ++j) {
                psum[j] += acc[r][j];
                psq[j]  += acc[r][j] * acc[r][j];
            }
        }
#pragma unroll
        for (int j = 0; j < 8; ++j) {
            atomicAdd(&redsum[cbase + j], psum[j]);
            atomicAdd(&redsq[cbase + j], psq[j]);
        }
        __syncthreads();
        if (tid < COUT) {
            partials[(size_t)gb * 256 + tid] = redsum[tid];
            partials[(size_t)gb * 256 + COUT + tid] = redsq[tid];
        }
    }
}

// ---------------------------------------------------------------------------
// 2) kNN, wave-cooperative: 1 wave per query (16 queries / 1024-thr block).
//    64 lanes compute 64 distances per step; top-16 lives as a sorted u64
//    key list, one element per lane in each row of 16. Inserts are rare
//    (~116/query), each a branchless DPP shift + 2 selects. Scan in index
//    order + strict < reproduces numpy top_k tie-breaks exactly.
//    Bit-exact _rn arithmetic (NOT the fma gamble -- bounded blast radius).
// ---------------------------------------------------------------------------
__global__ __launch_bounds__(1024, 1) void knn_kernel(const float* __restrict__ xyz,
                                                      const int* __restrict__ fps_idx,
                                                      int* __restrict__ knn_idx) {
    const int b = blockIdx.y;
    const int wv = threadIdx.x >> 6;      // 0..15
    const int lane = threadIdx.x & 63;
    const int q = blockIdx.x * 16 + wv;   // 0..2047
    const float* P = xyz + (size_t)b * N_ * 3;

    __shared__ float sx[N_], sy[N_], sz[N_];          // 96 KiB SoA
    for (int j = threadIdx.x; j < N_; j += 1024) {
        sx[j] = P[j * 3 + 0];
        sy[j] = P[j * 3 + 1];
        sz[j] = P[j * 3 + 2];
    }
    __syncthreads();

    const int qi = fps_idx[b * NPOINT + q];           // wave-uniform
    const float qx = sx[qi], qy = sy[qi], qz = sz[qi]; // broadcast LDS reads

    unsigned long long key = 0x7F800000FFFFFFFFull;
    float T = __builtin_bit_cast(float, 0x7F800000u);  // +inf

    for (int t = 0; t < N_ / 64; ++t) {
        const int i = (t << 6) + lane;
        float dx = __fsub_rn(qx, sx[i]);
        float dy = __fsub_rn(qy, sy[i]);
        float dz = __fsub_rn(qz, sz[i]);
        float d  = __fadd_rn(__fadd_rn(__fmul_rn(dx, dx), __fmul_rn(dy, dy)),
                             __fmul_rn(dz, dz));

        unsigned long long rem = __ballot(d < T);
        while (rem) {
            int L = __ffsll((long long)rem) - 1;
            unsigned cd = (unsigned)__builtin_amdgcn_readlane(
                              __builtin_bit_cast(int, d), L);
            unsigned long long c =
                ((unsigned long long)cd << 32) | (unsigned)((t << 6) + L);

            int klo = (int)(unsigned)(key & 0xFFFFFFFFull);
            int khi = (int)(unsigned)(key >> 32);
            int mlo = __builtin_amdgcn_update_dpp(0, klo, 0x111, 0xf, 0xf, true);
            int mhi = __builtin_amdgcn_update_dpp(0, khi, 0x111, 0xf, 0xf, true);
            unsigned long long m =
                ((unsigned long long)(unsigned)mhi << 32) | (unsigned)(unsigned)mlo;
            unsigned long long t1 = (m <= c) ? c : m;
            key = (key <= c) ? key : t1;

            int nhi = __builtin_amdgcn_readlane((int)(unsigned)(key >> 32), 15);
            T = __builtin_bit_cast(float, nhi);

            rem &= rem - 1;
            rem &= __ballot(d < T);
        }
    }

    if (lane < K_) {
        knn_idx[((size_t)b * NPOINT + q) * K_ + lane] =
            (int)(unsigned)(key & 0xFFFFFFFFull);
    }
}

// ---------------------------------------------------------------------------
// 3) BN finalize: parallel deterministic reduction over 1024 gemm blocks.
// ---------------------------------------------------------------------------
__global__ __launch_bounds__(256) void bn_finalize_kernel(const float* __restrict__ partials,
                                                          const float* __restrict__ gamma,
                                                          const float* __restrict__ beta,
                                                          float* __restrict__ stats) {
    const int c = blockIdx.x;             // 0..127
    const int t = threadIdx.x;            // 0..255
    float s = 0.f, sq = 0.f;
    for (int blk = t; blk < GEMM_BLOCKS; blk += 256) {
        s  += partials[(size_t)blk * 256 + c];
        sq += partials[(size_t)blk * 256 + COUT + c];
    }
    __shared__ float rs[256], rq[256];
    rs[t] = s; rq[t] = sq;
    __syncthreads();
    for (int off = 128; off > 0; off >>= 1) {
        if (t < off) { rs[t] += rs[t + off]; rq[t] += rq[t + off]; }
        __syncthreads();
    }
    if (t == 0) {
        const float invn = 1.0f / (float)(B_ * N_);
        float mean = rs[0] * invn;
        float var  = rq[0] * invn - mean * mean;
        float scale = gamma[c] / sqrtf(var + BN_EPS);
        float shift = beta[c] - mean * scale;
        stats[c] = scale;
        stats[COUT + c] = shift;
    }
}

// ---------------------------------------------------------------------------
// 4) Gather K neighbors, fused BN affine + ReLU, max-pool over K.
//    Block = 8 queries x 32 lanes, float4 per lane (16B/lane coalesced).
// ---------------------------------------------------------------------------
__global__ __launch_bounds__(256) void gather_max_kernel(const float* __restrict__ h,
                                                         const int* __restrict__ knn_idx,
                                                         const float* __restrict__ stats,
                                                         float* __restrict__ out) {
    const int lane = threadIdx.x & 31;
    const int qq = blockIdx.x * 8 + (threadIdx.x >> 5);  // global query [0, 32768)
    const int b = qq >> 11;
    const int c4 = lane * 4;
    const int* idx = knn_idx + (size_t)qq * K_;
    const float4 scale = *(const float4*)(stats + c4);
    const float4 shift = *(const float4*)(stats + COUT + c4);
    const float* hb = h + (size_t)b * N_ * COUT;
    float4 m = make_float4(-3.4e38f, -3.4e38f, -3.4e38f, -3.4e38f);
#pragma unroll
    for (int k = 0; k < K_; ++k) {
        const float4 v = *(const float4*)(hb + (size_t)idx[k] * COUT + c4);
        m.x = fmaxf(m.x, fmaxf(fmaf(v.x, scale.x, shift.x), 0.f));
        m.y = fmaxf(m.y, fmaxf(fmaf(v.y, scale.y, shift.y), 0.f));
        m.z = fmaxf(m.z, fmaxf(fmaf(v.z, scale.z, shift.z), 0.f));
        m.w = fmaxf(m.w, fmaxf(fmaf(v.w, scale.w, shift.w), 0.f));
    }
    *(float4*)(out + B_ * NPOINT * 3 + (size_t)qq * COUT + c4) = m;
}

// ---------------------------------------------------------------------------
extern "C" void kernel_launch(void* const* d_in, const int* in_sizes, int n_in,
                              void* d_out, int out_size, void* d_ws, size_t ws_size,
                              hipStream_t stream) {
    const float* xyz   = (const float*)d_in[0];  // [16,8192,3]
    const float* feat  = (const float*)d_in[1];  // [16,8192,64]
    const float* W     = (const float*)d_in[2];  // [128,64]
    const float* bias  = (const float*)d_in[3];  // [128]
    const float* gamma = (const float*)d_in[4];  // [128]
    const float* beta  = (const float*)d_in[5];  // [128]
    float* out = (float*)d_out;

    // workspace carving (all 256B-aligned by construction)
    char* ws = (char*)d_ws;
    int*   fps_idx  = (int*)(ws);                          // 16*2048*4        = 131072 B
    int*   knn_idx  = (int*)(ws + 131072);                 // 16*2048*16*4     = 2097152 B
    float* partials = (float*)(ws + 131072 + 2097152);     // 1024*256*4       = 1048576 B (2 MB carved)
    float* stats    = (float*)(ws + 131072 + 2097152 + 2097152);        // 256*4 = 1024 B
    float* h        = (float*)(ws + 131072 + 2097152 + 2097152 + 1024); // 16*8192*128*4 = 64 MiB

    // fps (blocks 0..15, ~2 ms on 16 CUs) + gemm (blocks 16..1039, hidden on
    // the other 240 CUs). newxyz fused into fps epilogue.
    fps_gemm_kernel<<<B_ + GEMM_BLOCKS, 1024, 0, stream>>>(
        xyz, fps_idx, out, feat, W, bias, h, partials);
    knn_kernel<<<dim3(NPOINT / 16, B_), 1024, 0, stream>>>(xyz, fps_idx, knn_idx);
    bn_finalize_kernel<<<COUT, 256, 0, stream>>>(partials, gamma, beta, stats);
    gather_max_kernel<<<(B_ * NPOINT) / 8, 256, 0, stream>>>(h, knn_idx, stats, out);
}

// Round 13
// 1959.593 us; speedup vs baseline: 1.6053x; 1.0026x over previous
//
#include <hip/hip_runtime.h>
#include <hip/hip_bf16.h>

// Problem constants (from reference)
#define B_    16
#define N_    8192
#define NPOINT 2048
#define K_    16
#define CIN   64
#define COUT  128
#define BN_EPS 1e-5f

#define GEMM_BLOCKS 1024              // 131072 rows / 128 rows per block

// f32 DPP max step (compiler folds mov_dpp into v_max_f32).
template <int CTRL>
__device__ __forceinline__ void fmax_step(float& v) {
    int b = __builtin_amdgcn_update_dpp(__builtin_bit_cast(int, v),
                                        __builtin_bit_cast(int, v),
                                        CTRL, 0xf, 0xf, false);
    v = fmaxf(v, __builtin_bit_cast(float, b));
}

// ---------------------------------------------------------------------------
// 1) FUSED fps + gemm: one launch, branch on blockIdx.x.
//    Blocks 0..15  : farthest point sampling (LDS atomicMax stage-2,
//                    write-once slots, LDS journal, fused new_xyz). Distance
//                    = fmaf(dz,dz, fmaf(dy,dy, dx*dx)) on exact _rn diffs --
//                    the r11-verified form (absmax 0.015625). The r12
//                    expanded-form |p|^2+|c|^2-2p.c REGRESSED (catastrophic
//                    cancellation flipped a selection, absmax 5.05): do NOT
//                    rearrange the subtract-then-square algebra; contraction
//                    of the existing order is the only safe fp change.
//    Blocks 16..   : fp32 GEMM h = feat @ W^T + b (128x128 tiles, 1024 thr)
//                    + per-block BN channel partials; hidden under fps on the
//                    other 240 CUs.
//    LDS is a union: fps needs 120 KB, gemm ~68 KB.
// ---------------------------------------------------------------------------
__global__ __launch_bounds__(1024, 1) void fps_gemm_kernel(
        const float* __restrict__ xyz, int* __restrict__ fps_idx,
        float* __restrict__ out_xyz,
        const float* __restrict__ feat, const float* __restrict__ W,
        const float* __restrict__ bias, float* __restrict__ h,
        float* __restrict__ partials) {
    __shared__ __align__(16) char smem[122880];      // 120 KB union

    if (blockIdx.x < B_) {
        // ===================== FPS path (16 blocks) =====================
        float* sx = (float*)smem;                    // [8192]
        float* sy = sx + N_;
        float* sz = sy + N_;
        int*   s_idx = (int*)(smem + 98304);         // [2048] journal
        unsigned long long* s_amax =
            (unsigned long long*)(smem + 106496);    // [2048] write-once slots

        const int b = blockIdx.x;
        const int t = threadIdx.x;
        const float* P = xyz + (size_t)b * N_ * 3;

        for (int j = t; j < N_; j += 1024) {
            sx[j] = P[j * 3 + 0];
            sy[j] = P[j * 3 + 1];
            sz[j] = P[j * 3 + 2];
        }
        for (int j = t; j < NPOINT; j += 1024) s_amax[j] = 0ull;
        if (t == 0) s_idx[0] = 0;
        __syncthreads();

        // lane-major ownership: thread t owns points [t*8, t*8+8)
        float px[8], py[8], pz[8], dist[8];
#pragma unroll
        for (int k = 0; k < 8; ++k) {
            int gi = t * 8 + k;
            px[k] = sx[gi];
            py[k] = sy[gi];
            pz[k] = sz[gi];
            dist[k] = 1e10f;
        }

        int cur = 0;
        const int wv_id = t >> 6;
        const int lane  = t & 63;

        for (int it = 1; it < NPOINT; ++it) {
            float cx = sx[cur], cy = sy[cur], cz = sz[cur];

            float bv = -1.0f; int bk = 0;
#pragma unroll
            for (int k = 0; k < 8; ++k) {
                float dx = __fsub_rn(px[k], cx);
                float dy = __fsub_rn(py[k], cy);
                float dz = __fsub_rn(pz[k], cz);
                // verified FMA contraction of the numpy order (r11)
                float d  = fmaf(dz, dz, fmaf(dy, dy, __fmul_rn(dx, dx)));
                float nd = fminf(dist[k], d);
                dist[k] = nd;
                // ascending k => ascending global index; strict > keeps lowest idx
                if (nd > bv) { bv = nd; bk = k; }
            }

            // stage 1: wave max via 6 DPP f32-max steps (lane 63 holds max)
            float m = bv;
            fmax_step<0x111>(m);
            fmax_step<0x112>(m);
            fmax_step<0x114>(m);
            fmax_step<0x118>(m);
            fmax_step<0x142>(m);
            fmax_step<0x143>(m);
            float M = __builtin_bit_cast(float,
                        __builtin_amdgcn_readlane(__builtin_bit_cast(int, m), 63));

            unsigned long long tied = __ballot(bv == M);
            int L   = __ffsll((long long)tied) - 1;
            int bkL = __builtin_amdgcn_readlane(bk, L);
            int gi  = ((wv_id << 6) + L) * 8 + bkL;

            // stage 2: one LDS atomicMax per wave into the write-once slot
            unsigned long long key =
                ((unsigned long long)__float_as_uint(M) << 32) |
                (unsigned long long)(unsigned)(N_ - 1 - gi);
            if (lane == 63) atomicMax(&s_amax[it], key);
            __syncthreads();

            unsigned long long mm = s_amax[it];
            cur = N_ - 1 - (int)(unsigned)(mm & 0xFFFFFFFFull);
            if (t == 0) s_idx[it] = cur;
        }

        __syncthreads();
        int* dst = fps_idx + b * NPOINT;
        float* oxyz = out_xyz + (size_t)b * NPOINT * 3;
        for (int q = t; q < NPOINT; q += 1024) {
            int idx = s_idx[q];
            dst[q] = idx;
            oxyz[q * 3 + 0] = sx[idx];
            oxyz[q * 3 + 1] = sy[idx];
            oxyz[q * 3 + 2] = sz[idx];
        }
    } else {
        // ===================== GEMM path (1024 blocks) ==================
        float* wT = (float*)smem;                    // [64][132] wT[c*132+o]
        float* fT = wT + 64 * 132;                   // [64][132] fT[c*132+r]
        float* redsum = fT + 64 * 132;               // [128]
        float* redsq  = redsum + COUT;               // [128]

        const int gb = blockIdx.x - B_;              // 0..1023
        const int tid = threadIdx.x;
        const size_t row0 = (size_t)gb * 128;

        for (int g = tid; g < COUT * CIN; g += 1024) {
            int o = g >> 6, c = g & 63;
            wT[c * 132 + o] = W[g];
        }
        for (int g = tid; g < 128 * CIN; g += 1024) {
            int r = g >> 6, c = g & 63;
            fT[c * 132 + r] = feat[(row0 + r) * CIN + c];
        }
        if (tid < COUT) { redsum[tid] = 0.f; redsq[tid] = 0.f; }
        __syncthreads();

        const int rbase = (tid >> 4) * 2;            // 0..126 step 2
        const int cbase = (tid & 15) * 8;            // 0..120 step 8

        float acc[2][8];
#pragma unroll
        for (int r = 0; r < 2; ++r)
#pragma unroll
            for (int j = 0; j < 8; ++j) acc[r][j] = bias[cbase + j];

        for (int c = 0; c < CIN; ++c) {
            const float2 f  = *(const float2*)(fT + c * 132 + rbase);
            const float4 w0 = *(const float4*)(wT + c * 132 + cbase);
            const float4 w1 = *(const float4*)(wT + c * 132 + cbase + 4);
            float wv[8] = {w0.x, w0.y, w0.z, w0.w, w1.x, w1.y, w1.z, w1.w};
#pragma unroll
            for (int j = 0; j < 8; ++j) {
                acc[0][j] = fmaf(f.x, wv[j], acc[0][j]);
                acc[1][j] = fmaf(f.y, wv[j], acc[1][j]);
            }
        }

        float psum[8], psq[8];
#pragma unroll
        for (int j = 0; j < 8; ++j) { psum[j] = 0.f; psq[j] = 0.f; }
#pragma unroll
        for (int r = 0; r < 2; ++r) {
            float4 v0 = make_float4(acc[r][0], acc[r][1], acc[r][2], acc[r][3]);
            float4 v1 = make_float4(acc[r][4], acc[r][5], acc[r][6], acc[r][7]);
            float4* dstp = (float4*)(h + (row0 + rbase + r) * COUT + cbase);
            dstp[0] = v0; dstp[1] = v1;
#pragma unroll
            for (int j = 0; j < 8; ++j) {
                psum[j] += acc[r][j];
                psq[j]  += acc[r][j] * acc[r][j];
            }
        }
#pragma unroll
        for (int j = 0; j < 8; ++j) {
            atomicAdd(&redsum[cbase + j], psum[j]);
            atomicAdd(&redsq[cbase + j], psq[j]);
        }
        __syncthreads();
        if (tid < COUT) {
            partials[(size_t)gb * 256 + tid] = redsum[tid];
            partials[(size_t)gb * 256 + COUT + tid] = redsq[tid];
        }
    }
}

// ---------------------------------------------------------------------------
// 2) kNN, wave-cooperative: 1 wave per query (16 queries / 1024-thr block).
//    64 lanes compute 64 distances per step; top-16 lives as a sorted u64
//    key list, one element per lane in each row of 16. Inserts are rare
//    (~116/query), each a branchless DPP shift + 2 selects. Scan in index
//    order + strict < reproduces numpy top_k tie-breaks exactly.
//    Bit-exact _rn arithmetic.
// ---------------------------------------------------------------------------
__global__ __launch_bounds__(1024, 1) void knn_kernel(const float* __restrict__ xyz,
                                                      const int* __restrict__ fps_idx,
                                                      int* __restrict__ knn_idx) {
    const int b = blockIdx.y;
    const int wv = threadIdx.x >> 6;      // 0..15
    const int lane = threadIdx.x & 63;
    const int q = blockIdx.x * 16 + wv;   // 0..2047
    const float* P = xyz + (size_t)b * N_ * 3;

    __shared__ float sx[N_], sy[N_], sz[N_];          // 96 KiB SoA
    for (int j = threadIdx.x; j < N_; j += 1024) {
        sx[j] = P[j * 3 + 0];
        sy[j] = P[j * 3 + 1];
        sz[j] = P[j * 3 + 2];
    }
    __syncthreads();

    const int qi = fps_idx[b * NPOINT + q];           // wave-uniform
    const float qx = sx[qi], qy = sy[qi], qz = sz[qi]; // broadcast LDS reads

    unsigned long long key = 0x7F800000FFFFFFFFull;
    float T = __builtin_bit_cast(float, 0x7F800000u);  // +inf

    for (int t = 0; t < N_ / 64; ++t) {
        const int i = (t << 6) + lane;
        float dx = __fsub_rn(qx, sx[i]);
        float dy = __fsub_rn(qy, sy[i]);
        float dz = __fsub_rn(qz, sz[i]);
        float d  = __fadd_rn(__fadd_rn(__fmul_rn(dx, dx), __fmul_rn(dy, dy)),
                             __fmul_rn(dz, dz));

        unsigned long long rem = __ballot(d < T);
        while (rem) {
            int L = __ffsll((long long)rem) - 1;
            unsigned cd = (unsigned)__builtin_amdgcn_readlane(
                              __builtin_bit_cast(int, d), L);
            unsigned long long c =
                ((unsigned long long)cd << 32) | (unsigned)((t << 6) + L);

            int klo = (int)(unsigned)(key & 0xFFFFFFFFull);
            int khi = (int)(unsigned)(key >> 32);
            int mlo = __builtin_amdgcn_update_dpp(0, klo, 0x111, 0xf, 0xf, true);
            int mhi = __builtin_amdgcn_update_dpp(0, khi, 0x111, 0xf, 0xf, true);
            unsigned long long m =
                ((unsigned long long)(unsigned)mhi << 32) | (unsigned)(unsigned)mlo;
            unsigned long long t1 = (m <= c) ? c : m;
            key = (key <= c) ? key : t1;

            int nhi = __builtin_amdgcn_readlane((int)(unsigned)(key >> 32), 15);
            T = __builtin_bit_cast(float, nhi);

            rem &= rem - 1;
            rem &= __ballot(d < T);
        }
    }

    if (lane < K_) {
        knn_idx[((size_t)b * NPOINT + q) * K_ + lane] =
            (int)(unsigned)(key & 0xFFFFFFFFull);
    }
}

// ---------------------------------------------------------------------------
// 3) BN finalize: parallel deterministic reduction over 1024 gemm blocks.
// ---------------------------------------------------------------------------
__global__ __launch_bounds__(256) void bn_finalize_kernel(const float* __restrict__ partials,
                                                          const float* __restrict__ gamma,
                                                          const float* __restrict__ beta,
                                                          float* __restrict__ stats) {
    const int c = blockIdx.x;             // 0..127
    const int t = threadIdx.x;            // 0..255
    float s = 0.f, sq = 0.f;
    for (int blk = t; blk < GEMM_BLOCKS; blk += 256) {
        s  += partials[(size_t)blk * 256 + c];
        sq += partials[(size_t)blk * 256 + COUT + c];
    }
    __shared__ float rs[256], rq[256];
    rs[t] = s; rq[t] = sq;
    __syncthreads();
    for (int off = 128; off > 0; off >>= 1) {
        if (t < off) { rs[t] += rs[t + off]; rq[t] += rq[t + off]; }
        __syncthreads();
    }
    if (t == 0) {
        const float invn = 1.0f / (float)(B_ * N_);
        float mean = rs[0] * invn;
        float var  = rq[0] * invn - mean * mean;
        float scale = gamma[c] / sqrtf(var + BN_EPS);
        float shift = beta[c] - mean * scale;
        stats[c] = scale;
        stats[COUT + c] = shift;
    }
}

// ---------------------------------------------------------------------------
// 4) Gather K neighbors, fused BN affine + ReLU, max-pool over K.
//    Block = 8 queries x 32 lanes, float4 per lane (16B/lane coalesced).
// ---------------------------------------------------------------------------
__global__ __launch_bounds__(256) void gather_max_kernel(const float* __restrict__ h,
                                                         const int* __restrict__ knn_idx,
                                                         const float* __restrict__ stats,
                                                         float* __restrict__ out) {
    const int lane = threadIdx.x & 31;
    const int qq = blockIdx.x * 8 + (threadIdx.x >> 5);  // global query [0, 32768)
    const int b = qq >> 11;
    const int c4 = lane * 4;
    const int* idx = knn_idx + (size_t)qq * K_;
    const float4 scale = *(const float4*)(stats + c4);
    const float4 shift = *(const float4*)(stats + COUT + c4);
    const float* hb = h + (size_t)b * N_ * COUT;
    float4 m = make_float4(-3.4e38f, -3.4e38f, -3.4e38f, -3.4e38f);
#pragma unroll
    for (int k = 0; k < K_; ++k) {
        const float4 v = *(const float4*)(hb + (size_t)idx[k] * COUT + c4);
        m.x = fmaxf(m.x, fmaxf(fmaf(v.x, scale.x, shift.x), 0.f));
        m.y = fmaxf(m.y, fmaxf(fmaf(v.y, scale.y, shift.y), 0.f));
        m.z = fmaxf(m.z, fmaxf(fmaf(v.z, scale.z, shift.z), 0.f));
        m.w = fmaxf(m.w, fmaxf(fmaf(v.w, scale.w, shift.w), 0.f));
    }
    *(float4*)(out + B_ * NPOINT * 3 + (size_t)qq * COUT + c4) = m;
}

// ---------------------------------------------------------------------------
extern "C" void kernel_launch(void* const* d_in, const int* in_sizes, int n_in,
                              void* d_out, int out_size, void* d_ws, size_t ws_size,
                              hipStream_t stream) {
    const float* xyz   = (const float*)d_in[0];  // [16,8192,3]
    const float* feat  = (const float*)d_in[1];  // [16,8192,64]
    const float* W     = (const float*)d_in[2];  // [128,64]
    const float* bias  = (const float*)d_in[3];  // [128]
    const float* gamma = (const float*)d_in[4];  // [128]
    const float* beta  = (const float*)d_in[5];  // [128]
    float* out = (float*)d_out;

    // workspace carving (all 256B-aligned by construction)
    char* ws = (char*)d_ws;
    int*   fps_idx  = (int*)(ws);                          // 16*2048*4        = 131072 B
    int*   knn_idx  = (int*)(ws + 131072);                 // 16*2048*16*4     = 2097152 B
    float* partials = (float*)(ws + 131072 + 2097152);     // 1024*256*4       = 1048576 B (2 MB carved)
    float* stats    = (float*)(ws + 131072 + 2097152 + 2097152);        // 256*4 = 1024 B
    float* h        = (float*)(ws + 131072 + 2097152 + 2097152 + 1024); // 16*8192*128*4 = 64 MiB

    // fps (blocks 0..15, ~1.6 ms on 16 CUs) + gemm (blocks 16..1039, hidden
    // on the other 240 CUs). newxyz fused into fps epilogue.
    fps_gemm_kernel<<<B_ + GEMM_BLOCKS, 1024, 0, stream>>>(
        xyz, fps_idx, out, feat, W, bias, h, partials);
    knn_kernel<<<dim3(NPOINT / 16, B_), 1024, 0, stream>>>(xyz, fps_idx, knn_idx);
    bn_finalize_kernel<<<COUT, 256, 0, stream>>>(partials, gamma, beta, stats);
    gather_max_kernel<<<(B_ * NPOINT) / 8, 256, 0, stream>>>(h, knn_idx, stats, out);
}